// Round 13
// baseline (652.181 us; speedup 1.0000x reference)
//
#include <hip/hip_runtime.h>

// LSTM predictor: B=1024, T=1024, H=51, input=1. Sequential recurrence.
//
// Round 13. Empirical law from rounds 1-12: the register allocator grants
// only ~88-132 arch VGPRs in barriered loop code no matter what attributes
// or asm pins are used (use-site "v" asm doesn't help either -- it just
// inserts accvgpr_read copies). So: design under an ~80-VGPR demand.
//
// 4-wave GATE-split (vs round-5's k-split): wave g owns gate g; lane l
// owns unit l -> 51 weights/lane (one W_hh row), total demand ~70 VGPRs.
//  - h via per-wave LDS replica, 13 uniform ds_read_b128 broadcasts.
//  - One activation per lane per step, wave-uniform branch (g==2 -> tanh).
//  - ONE barrier/step: act exchange, parity double-buffered (rounds 6/11/12
//    proven). All 4 waves then compute the bit-identical c/h update
//    redundantly; each writes its own h replica (no cross-wave h dep).
//  - 1024 blocks x 4 waves = 4 waves/SIMD: first round with real latency
//    hiding (prior rounds ran 1-2 waves/SIMD; every bubble was exposed).
//  - fc output staged by wave 0 in stride-65 LDS, reduced every 64 steps.

#define HID 51
#define SEQ_T 1024

static __device__ __forceinline__ float lane_bcast(float v, int lane) {
    return __int_as_float(__builtin_amdgcn_readlane(__float_as_int(v), lane));
}
static __device__ __forceinline__ float fast_sigmoid(float x) {
    float e = __builtin_amdgcn_exp2f(x * -1.44269504088896340736f);
    return __builtin_amdgcn_rcpf(1.0f + e);
}
static __device__ __forceinline__ float fast_tanh(float x) {
    float e = __builtin_amdgcn_exp2f(x * 2.88539008177792681472f);
    return 1.0f - 2.0f * __builtin_amdgcn_rcpf(e + 1.0f);
}

__global__ __launch_bounds__(256)
__attribute__((amdgpu_waves_per_eu(4, 4)))
void lstm_gate4_kernel(
    const float* __restrict__ x,      // [B, T]
    const float* __restrict__ W_ih,   // [4H, 1]
    const float* __restrict__ W_hh,   // [4H, H]
    const float* __restrict__ b_ih,   // [4H]
    const float* __restrict__ b_hh,   // [4H]
    const float* __restrict__ fc_w,   // [1, H]
    const float* __restrict__ fc_b,   // [1]
    float* __restrict__ out)          // [B, T]
{
    const int b = blockIdx.x;
    const int tid = threadIdx.x;
    const int g = tid >> 6;   // wave index == gate index (i,f,g,o)
    const int l = tid & 63;   // lane == hidden unit
    const bool on = (l < HID);

    __shared__ __align__(16) float hrep[4][64];  // per-wave fp32 h replica
    __shared__ float actb[2][4][64];             // [parity][gate][lane]
    __shared__ float pbuf[64][65];               // fc staging (wave 0)

    // ---- per-lane weights: ONE gate row of W_hh = 51 fp32 (+1 pad) ----
    float wq[HID + 1];
#pragma unroll
    for (int k = 0; k < HID; ++k) {
        wq[k] = on ? W_hh[(g * HID + l) * HID + k] : 0.f;
        asm volatile("" : "+v"(wq[k]));  // anchor load before the loop
    }
    wq[HID] = 0.f;  // k=51 pad (h pad slot is 0 anyway)

    const float bias = on ? b_ih[g * HID + l] + b_hh[g * HID + l] : 0.f;
    const float wx   = on ? W_ih[g * HID + l] : 0.f;
    const float fcw  = on ? fc_w[l] : 0.f;
    const float fcb  = fc_b[0];
    float c = 0.f;

    hrep[g][l] = 0.f;  // own replica: same-wave write->read, lgkm-ordered
    const float4* __restrict__ hq4 = (const float4*)(&hrep[g][0]);

#pragma unroll 1
    for (int t0 = 0; t0 < SEQ_T; t0 += 64) {
        const float xv = x[b * SEQ_T + t0 + l];  // 64 steps of input

#pragma unroll 1
        for (int i = 0; i < 64; ++i) {
            // ---- my gate's dot product over own h replica ----
            const float xt = lane_bcast(xv, i);
            float s0 = fmaf(xt, wx, bias), s1 = 0.f;
#pragma unroll
            for (int q = 0; q < 13; ++q) {
                const float4 h4 = hq4[q];  // uniform addr -> broadcast read
                s0 = fmaf(h4.x, wq[4 * q + 0], s0);
                s1 = fmaf(h4.y, wq[4 * q + 1], s1);
                s0 = fmaf(h4.z, wq[4 * q + 2], s0);
                s1 = fmaf(h4.w, wq[4 * q + 3], s1);
            }
            const float s = s0 + s1;

            // one activation per lane; branch is wave-uniform
            const float a = (g == 2) ? fast_tanh(s) : fast_sigmoid(s);
            const int par = i & 1;
            actb[par][g][l] = a;         // stride-1 write, conflict-free
            __syncthreads();             // the ONE barrier per step

            // ---- redundant c/h update (bit-identical on all 4 waves) ----
            const float ig = actb[par][0][l];
            const float fg = actb[par][1][l];
            const float gg = actb[par][2][l];
            const float og = actb[par][3][l];
            c = fmaf(fg, c, ig * gg);
            const float hn = og * fast_tanh(c);
            // pad lanes: zero weights/bias -> s=0 -> i=f=o=0.5, g=0 ->
            // c stays 0 -> hn exactly 0: h pad slots stay 0.
            hrep[g][l] = hn;

            if (g == 0) pbuf[l][i] = hn * fcw;  // fc staging
        }

        if (g == 0) {
            float s2r = 0.f;
#pragma unroll
            for (int k = 0; k < HID; ++k) s2r += pbuf[k][l];  // stride-1
            out[b * SEQ_T + t0 + l] = s2r + fcb;  // coalesced 64-chunk
        }
    }
}

extern "C" void kernel_launch(void* const* d_in, const int* in_sizes, int n_in,
                              void* d_out, int out_size, void* d_ws, size_t ws_size,
                              hipStream_t stream) {
    (void)in_sizes; (void)n_in; (void)d_ws; (void)ws_size; (void)out_size;
    const float* x    = (const float*)d_in[0];
    const float* W_ih = (const float*)d_in[1];
    const float* W_hh = (const float*)d_in[2];
    const float* b_ih = (const float*)d_in[3];
    const float* b_hh = (const float*)d_in[4];
    const float* fc_w = (const float*)d_in[5];
    const float* fc_b = (const float*)d_in[6];
    float* out = (float*)d_out;

    lstm_gate4_kernel<<<dim3(1024), dim3(256), 0, stream>>>(
        x, W_ih, W_hh, b_ih, b_hh, fc_w, fc_b, out);
}